// Round 3
// baseline (792.324 us; speedup 1.0000x reference)
//
#include <hip/hip_runtime.h>
#include <hip/hip_bf16.h>

#define NUM_LAYERS 32
#define HIDDEN 2048
#define RANK 64
#define BATCH 2048
#define HC 256              // h-chunk per k_proj/k_delta block (4 waves x 64)
#define NCH (HIDDEN / HC)   // 8 chunks
#define CH 16               // samples per block-iteration
#define SC 4                // sample-chunk split (grid z)
#define UPAD 260            // ushort stride for LDS-transposed u tile (bank-safe)

// Workspace layout:
//   partial [NCH][BATCH][RANK] f32 : per-chunk proj partials (4 MB, fully written)
//   proj    [BATCH][RANK]      f32 : reduced projections (512 KB)
//   counts[32], offsets[32], perm[BATCH] ints

__global__ __launch_bounds__(256)
void k_bucket(const int* __restrict__ ids, int* __restrict__ counts,
              int* __restrict__ offsets, int* __restrict__ perm)
{
    __shared__ int cnt[NUM_LAYERS];
    __shared__ int off[NUM_LAYERS];
    __shared__ int cur[NUM_LAYERS];
    const int t = threadIdx.x;
    if (t < NUM_LAYERS) cnt[t] = 0;
    __syncthreads();
    for (int i = t; i < BATCH; i += 256) atomicAdd(&cnt[ids[i]], 1);
    __syncthreads();
    if (t == 0) {
        int a = 0;
        for (int l = 0; l < NUM_LAYERS; ++l) { off[l] = a; a += cnt[l]; }
    }
    __syncthreads();
    if (t < NUM_LAYERS) { cur[t] = 0; counts[t] = cnt[t]; offsets[t] = off[t]; }
    __syncthreads();
    for (int i = t; i < BATCH; i += 256) {
        int l = ids[i];
        int p = off[l] + atomicAdd(&cur[l], 1);
        perm[p] = i;
    }
}

// K1: partial[c][b][r] = sum_{h in chunk c} v[l,h,r] * z[b,h]
// grid (NCH, NUM_LAYERS, SC) x 256. Wave g owns 64 h; lane r holds the
// v column segment in 64 VGPRs (coalesced load). No atomics: coalesced
// partial stores, summed later by k_reduce.
__global__ __launch_bounds__(256, 4)
void k_proj(const float* __restrict__ z, const float* __restrict__ v,
            const int* __restrict__ counts, const int* __restrict__ offsets,
            const int* __restrict__ perm, float* __restrict__ partial)
{
    const int c = blockIdx.x, l = blockIdx.y, sc = blockIdx.z;
    const int n = counts[l], o = offsets[l];
    if (sc * CH >= n) return;                       // early-out BEFORE prologue
    const int t = threadIdx.x;
    const int g = t >> 6, lane = t & 63;
    const int hbase = c * HC + g * 64;

    // v slice: lane=r -> consecutive addresses, fully coalesced
    float vr[64];
    const float* vp = v + ((size_t)l * HIDDEN + hbase) * RANK + lane;
    #pragma unroll
    for (int i = 0; i < 64; ++i) vr[i] = vp[(size_t)i * RANK];

    __shared__ float zs[4][CH][64];     // wave-local staged z slabs (16 KB)
    __shared__ float red[CH][4][RANK];  // cross-wave partials (16 KB)

    for (int base = sc * CH; base < n; base += SC * CH) {
        const int nb = (n - base < CH) ? (n - base) : CH;
        __syncthreads();                // protect red/zs reuse across iters
        // stage 16x64 slab, 4 coalesced float4 loads per lane
        #pragma unroll
        for (int k = 0; k < 4; ++k) {
            const int si = k * 4 + (lane >> 4);
            const int rq = lane & 15;
            if (si < nb) {
                const int b = perm[o + base + si];
                const float4 zv = *(const float4*)&z[(size_t)b * HIDDEN + hbase + rq * 4];
                *(float4*)&zs[g][si][rq * 4] = zv;
            }
        }
        __syncthreads();

        float acc[CH];
        #pragma unroll
        for (int si = 0; si < CH; ++si) acc[si] = 0.0f;

        #pragma unroll
        for (int i4 = 0; i4 < 16; ++i4) {
            #pragma unroll
            for (int si = 0; si < CH; ++si) {
                const float4 zv = *(const float4*)&zs[g][si][i4 * 4]; // broadcast
                acc[si] += vr[i4 * 4 + 0] * zv.x + vr[i4 * 4 + 1] * zv.y
                         + vr[i4 * 4 + 2] * zv.z + vr[i4 * 4 + 3] * zv.w;
            }
        }

        #pragma unroll
        for (int si = 0; si < CH; ++si) red[si][g][lane] = acc[si];
        __syncthreads();
        // each wave reduces 4 samples, coalesced store (no atomics)
        #pragma unroll
        for (int s2 = 0; s2 < 4; ++s2) {
            const int si = s2 * 4 + g;
            if (si < nb) {
                const int b = perm[o + base + si];
                partial[((size_t)c * BATCH + b) * RANK + lane] =
                    red[si][0][lane] + red[si][1][lane]
                  + red[si][2][lane] + red[si][3][lane];
            }
        }
    }
}

// K2: proj[b][r] = sum_c partial[c][b][r]
__global__ __launch_bounds__(256)
void k_reduce(const float* __restrict__ partial, float* __restrict__ proj)
{
    const int i = (blockIdx.x * 256 + threadIdx.x) * 4;   // over BATCH*RANK
    float4 s = *(const float4*)&partial[i];
    #pragma unroll
    for (int c = 1; c < NCH; ++c) {
        const float4 p = *(const float4*)&partial[(size_t)c * BATCH * RANK + i];
        s.x += p.x; s.y += p.y; s.z += p.z; s.w += p.w;
    }
    *(float4*)&proj[i] = s;
}

// K3: out[b,h] = z[b,h] + sum_r u[l,h,r] * proj[b,r]
// u tile staged coalesced -> LDS bf16 transposed -> per-thread register row.
__global__ __launch_bounds__(256, 4)
void k_delta(const float* __restrict__ z, const float* __restrict__ u,
             const int* __restrict__ counts, const int* __restrict__ offsets,
             const int* __restrict__ perm, const float* __restrict__ proj,
             float* __restrict__ out)
{
    const int c = blockIdx.x, l = blockIdx.y, sc = blockIdx.z;
    const int n = counts[l], o = offsets[l];
    if (sc * CH >= n) return;
    const int t = threadIdx.x;
    const int h = c * HC + t;

    __shared__ ushort utl[RANK * UPAD];   // transposed bf16 u tile (~33 KB)
    __shared__ float  ps[CH][RANK];       // staged proj rows (4 KB)

    // stage u[l, c*HC .. +255, 0..63] coalesced (16 rows x 256B per wave-instr),
    // write bf16 transposed into LDS
    #pragma unroll
    for (int k = 0; k < 16; ++k) {
        const int hh = (t >> 4) + k * 16;
        const int q  = t & 15;
        const float4 uv = *(const float4*)
            &u[((size_t)l * HIDDEN + c * HC + hh) * RANK + q * 4];
        __hip_bfloat16 b0 = __float2bfloat16(uv.x);
        __hip_bfloat16 b1 = __float2bfloat16(uv.y);
        __hip_bfloat16 b2 = __float2bfloat16(uv.z);
        __hip_bfloat16 b3 = __float2bfloat16(uv.w);
        utl[(q * 4 + 0) * UPAD + hh] = *(const ushort*)&b0;
        utl[(q * 4 + 1) * UPAD + hh] = *(const ushort*)&b1;
        utl[(q * 4 + 2) * UPAD + hh] = *(const ushort*)&b2;
        utl[(q * 4 + 3) * UPAD + hh] = *(const ushort*)&b3;
    }
    __syncthreads();

    // pull my h-column of the tile into 64 registers (conflict-free: 2 lanes/bank)
    float ur[64];
    #pragma unroll
    for (int r = 0; r < 64; ++r) {
        const unsigned int bits = ((unsigned int)utl[r * UPAD + t]) << 16;
        ur[r] = __builtin_bit_cast(float, bits);
    }

    for (int base = sc * CH; base < n; base += SC * CH) {
        const int nb = (n - base < CH) ? (n - base) : CH;
        __syncthreads();                // protect ps reuse across iters
        #pragma unroll
        for (int k = 0; k < 4; ++k) {
            const int idx = t + k * 256;
            const int si = idx >> 6, r = idx & 63;
            if (si < nb) {
                const int b = perm[o + base + si];
                ps[si][r] = proj[(size_t)b * RANK + r];
            }
        }
        __syncthreads();

        float acc[CH];
        #pragma unroll
        for (int si = 0; si < CH; ++si) acc[si] = 0.0f;

        #pragma unroll
        for (int i4 = 0; i4 < 16; ++i4) {
            #pragma unroll
            for (int si = 0; si < CH; ++si) {
                const float4 p4 = *(const float4*)&ps[si][i4 * 4]; // broadcast
                acc[si] += ur[i4 * 4 + 0] * p4.x + ur[i4 * 4 + 1] * p4.y
                         + ur[i4 * 4 + 2] * p4.z + ur[i4 * 4 + 3] * p4.w;
            }
        }

        for (int si = 0; si < nb; ++si) {
            const int b = perm[o + base + si];
            out[(size_t)b * HIDDEN + h] = z[(size_t)b * HIDDEN + h] + acc[si];
        }
    }
}

extern "C" void kernel_launch(void* const* d_in, const int* in_sizes, int n_in,
                              void* d_out, int out_size, void* d_ws, size_t ws_size,
                              hipStream_t stream)
{
    const float* z   = (const float*)d_in[0];
    const int*   ids = (const int*)d_in[1];
    const float* u   = (const float*)d_in[2];
    const float* v   = (const float*)d_in[3];
    float* out = (float*)d_out;

    float* partial = (float*)d_ws;                         // 4 MB
    float* proj    = partial + (size_t)NCH * BATCH * RANK; // 512 KB
    int* counts    = (int*)(proj + (size_t)BATCH * RANK);
    int* offsets   = counts + NUM_LAYERS;
    int* perm      = offsets + NUM_LAYERS;

    hipLaunchKernelGGL(k_bucket, dim3(1), dim3(256), 0, stream,
                       ids, counts, offsets, perm);
    hipLaunchKernelGGL(k_proj, dim3(NCH, NUM_LAYERS, SC), dim3(256), 0, stream,
                       z, v, counts, offsets, perm, partial);
    hipLaunchKernelGGL(k_reduce, dim3(BATCH * RANK / 4 / 256), dim3(256), 0, stream,
                       partial, proj);
    hipLaunchKernelGGL(k_delta, dim3(NCH, NUM_LAYERS, SC), dim3(256), 0, stream,
                       z, u, counts, offsets, perm, proj, out);
}

// Round 4
// 157.222 us; speedup vs baseline: 5.0395x; 5.0395x over previous
//
#include <hip/hip_runtime.h>
#include <hip/hip_bf16.h>

#define NUM_LAYERS 32
#define HIDDEN 2048
#define RANK 64
#define BATCH 2048
#define HC 256              // h-chunk per block (4 waves x 64)
#define NCH (HIDDEN / HC)   // 8 chunks
#define CH 16               // samples per block-iteration
#define SC 4                // sample-chunk split (grid z)
#define UPAD 257            // ushort stride for transposed bf16 u tile

// Workspace: proj [BATCH][RANK] f32 (zeroed by K0), counts[32], offsets[32], perm[BATCH]

static __device__ __forceinline__ ushort f2bf(float x) {
    unsigned b = __builtin_bit_cast(unsigned, x);
    b += 0x7fffu + ((b >> 16) & 1u);          // round-to-nearest-even
    return (ushort)(b >> 16);
}

__global__ __launch_bounds__(256)
void k_bucket_zero(const int* __restrict__ ids, float* __restrict__ proj,
                   int* __restrict__ counts, int* __restrict__ offsets,
                   int* __restrict__ perm)
{
    if (blockIdx.x == 0) {
        __shared__ int cnt[NUM_LAYERS];
        __shared__ int off[NUM_LAYERS];
        __shared__ int cur[NUM_LAYERS];
        const int t = threadIdx.x;
        if (t < NUM_LAYERS) cnt[t] = 0;
        __syncthreads();
        for (int i = t; i < BATCH; i += 256) atomicAdd(&cnt[ids[i]], 1);
        __syncthreads();
        if (t == 0) {
            int a = 0;
            for (int l = 0; l < NUM_LAYERS; ++l) { off[l] = a; a += cnt[l]; }
        }
        __syncthreads();
        if (t < NUM_LAYERS) { cur[t] = 0; counts[t] = cnt[t]; offsets[t] = off[t]; }
        __syncthreads();
        for (int i = t; i < BATCH; i += 256) {
            int l = ids[i];
            int p = off[l] + atomicAdd(&cur[l], 1);
            perm[p] = i;
        }
    } else {
        // blocks 1..64 zero proj: 131072 floats / 64 blocks = 2048 each
        const int base = (blockIdx.x - 1) * (BATCH * RANK / 64);
        for (int i = threadIdx.x; i < BATCH * RANK / 64; i += 256)
            proj[base + i] = 0.0f;
    }
}

// K1: proj[b,r] += sum_{h in chunk} v[l,h,r] * z[b,h]
// Wave g owns 64 h; lane = r. v column segment in 64 VGPRs (coalesced).
// z row values are wave-uniform -> scalar loads feeding v_fmac (no LDS in
// the inner loop). Cross-wave LDS reduction, then atomicAdd into proj.
__global__ __launch_bounds__(256)
void k_proj(const float* __restrict__ z, const float* __restrict__ v,
            const int* __restrict__ counts, const int* __restrict__ offsets,
            const int* __restrict__ perm, float* __restrict__ proj)
{
    const int c = blockIdx.x, l = blockIdx.y, sc = blockIdx.z;
    const int n = counts[l], o = offsets[l];
    if (sc * CH >= n) return;                 // early-out BEFORE prologue
    const int t = threadIdx.x;
    const int g = t >> 6, lane = t & 63;
    const int hbase = c * HC + g * 64;

    // v slice: lane=r -> consecutive addresses, 1 line per wave-instr
    float vr[64];
    const float* vp = v + ((size_t)l * HIDDEN + hbase) * RANK + lane;
    #pragma unroll
    for (int i = 0; i < 64; ++i) vr[i] = vp[(size_t)i * RANK];

    __shared__ float red[CH][4][RANK];        // 16 KB cross-wave partials

    for (int base = sc * CH; base < n; base += SC * CH) {
        const int nb = (n - base < CH) ? (n - base) : CH;

        float acc[CH];
        #pragma unroll
        for (int si = 0; si < CH; ++si) acc[si] = 0.0f;

        #pragma unroll
        for (int si = 0; si < CH; ++si) {
            if (si < nb) {                    // uniform branch
                const int b = __builtin_amdgcn_readfirstlane(perm[o + base + si]);
                const float* zb = z + (size_t)b * HIDDEN + hbase;
                #pragma unroll
                for (int j = 0; j < 64; ++j)
                    acc[si] += vr[j] * zb[j]; // zb[j] uniform -> s_load + v_fmac
            }
        }

        __syncthreads();                      // protect red reuse across iters
        #pragma unroll
        for (int si = 0; si < CH; ++si) red[si][g][lane] = acc[si];
        __syncthreads();
        #pragma unroll
        for (int s2 = 0; s2 < 4; ++s2) {
            const int si = s2 * 4 + g;        // wave g reduces samples g,4+g,...
            if (si < nb) {
                const int b = perm[o + base + si];
                atomicAdd(&proj[(size_t)b * RANK + lane],
                          red[si][0][lane] + red[si][1][lane]
                        + red[si][2][lane] + red[si][3][lane]);
            }
        }
    }
}

// K2: out[b,h] = z[b,h] + sum_r u[l,h,r] * proj[b,r]
// u tile staged coalesced -> bf16 transposed LDS -> per-thread 64-reg row.
// proj row is wave-uniform -> scalar loads feeding v_fmac. z/out coalesced.
__global__ __launch_bounds__(256)
void k_delta(const float* __restrict__ z, const float* __restrict__ u,
             const int* __restrict__ counts, const int* __restrict__ offsets,
             const int* __restrict__ perm, const float* __restrict__ proj,
             float* __restrict__ out)
{
    const int c = blockIdx.x, l = blockIdx.y, sc = blockIdx.z;
    const int n = counts[l], o = offsets[l];
    if (sc * CH >= n) return;
    const int t = threadIdx.x;
    const int h = c * HC + t;

    __shared__ ushort utl[RANK * UPAD];       // 64 x 257 shorts = 32.9 KB

    // stage u[l, c*HC .. +255, 0..63]: fully coalesced float4 reads,
    // bf16-transposed LDS writes (once per block)
    #pragma unroll
    for (int k = 0; k < 16; ++k) {
        const int hh = k * 16 + (t >> 4);
        const int q  = t & 15;
        const float4 uv = *(const float4*)
            &u[((size_t)l * HIDDEN + c * HC + hh) * RANK + q * 4];
        utl[(q * 4 + 0) * UPAD + hh] = f2bf(uv.x);
        utl[(q * 4 + 1) * UPAD + hh] = f2bf(uv.y);
        utl[(q * 4 + 2) * UPAD + hh] = f2bf(uv.z);
        utl[(q * 4 + 3) * UPAD + hh] = f2bf(uv.w);
    }
    __syncthreads();

    // my h-column -> 64 registers (2 lanes/bank: conflict-free)
    float ur[64];
    #pragma unroll
    for (int r = 0; r < 64; ++r) {
        const unsigned bits = ((unsigned)utl[r * UPAD + t]) << 16;
        ur[r] = __builtin_bit_cast(float, bits);
    }

    for (int base = sc * CH; base < n; base += SC * CH) {
        const int nb = (n - base < CH) ? (n - base) : CH;
        #pragma unroll
        for (int si = 0; si < CH; ++si) {
            if (si < nb) {                    // uniform branch
                const int b = __builtin_amdgcn_readfirstlane(perm[o + base + si]);
                const float* pb = proj + (size_t)b * RANK;
                float acc = 0.0f;
                #pragma unroll
                for (int r = 0; r < 64; ++r)
                    acc += ur[r] * pb[r];     // pb[r] uniform -> s_load + v_fmac
                out[(size_t)b * HIDDEN + h] = z[(size_t)b * HIDDEN + h] + acc;
            }
        }
    }
}

extern "C" void kernel_launch(void* const* d_in, const int* in_sizes, int n_in,
                              void* d_out, int out_size, void* d_ws, size_t ws_size,
                              hipStream_t stream)
{
    const float* z   = (const float*)d_in[0];
    const int*   ids = (const int*)d_in[1];
    const float* u   = (const float*)d_in[2];
    const float* v   = (const float*)d_in[3];
    float* out = (float*)d_out;

    float* proj   = (float*)d_ws;                          // 512 KB
    int* counts   = (int*)(proj + (size_t)BATCH * RANK);
    int* offsets  = counts + NUM_LAYERS;
    int* perm     = offsets + NUM_LAYERS;

    hipLaunchKernelGGL(k_bucket_zero, dim3(65), dim3(256), 0, stream,
                       ids, proj, counts, offsets, perm);
    hipLaunchKernelGGL(k_proj, dim3(NCH, NUM_LAYERS, SC), dim3(256), 0, stream,
                       z, v, counts, offsets, perm, proj);
    hipLaunchKernelGGL(k_delta, dim3(NCH, NUM_LAYERS, SC), dim3(256), 0, stream,
                       z, u, counts, offsets, perm, proj, out);
}

// Round 5
// 111.010 us; speedup vs baseline: 7.1374x; 1.4163x over previous
//
#include <hip/hip_runtime.h>

#define NUM_LAYERS 32
#define HIDDEN 2048
#define RANK 64
#define BATCH 2048
#define KC 256               // h-chunk (K) per k_proj block
#define HCH 256              // h-chunk (N) per k_delta block
#define MB 32                // samples per pass (2 M-tiles)
#define SCG 2                // sample-chunk grid split (loop covers any n)
#define ZPAD 264             // ushort row stride, z tile  (16B-aligned, bank-safe)
#define VPAD 264             // ushort row stride, v tile
#define UPAD 72              // ushort row stride, u tile
#define PPAD 72              // ushort row stride, p tile

typedef __attribute__((ext_vector_type(8))) short bf16x8;
typedef __attribute__((ext_vector_type(4))) float f32x4;

static __device__ __forceinline__ ushort f2bf(float x) {
    unsigned b = __builtin_bit_cast(unsigned, x);
    b += 0x7fffu + ((b >> 16) & 1u);          // round-to-nearest-even
    return (ushort)(b >> 16);
}
static __device__ __forceinline__ ushort4 pack4(float4 v) {
    ushort4 r; r.x = f2bf(v.x); r.y = f2bf(v.y); r.z = f2bf(v.z); r.w = f2bf(v.w);
    return r;
}

// Workspace: proj [BATCH][RANK] f32 (zeroed), counts[32], offsets[32], perm[BATCH]
__global__ __launch_bounds__(256)
void k_bucket_zero(const int* __restrict__ ids, float* __restrict__ proj,
                   int* __restrict__ counts, int* __restrict__ offsets,
                   int* __restrict__ perm)
{
    if (blockIdx.x == 0) {
        __shared__ int cnt[NUM_LAYERS];
        __shared__ int off[NUM_LAYERS];
        __shared__ int cur[NUM_LAYERS];
        const int t = threadIdx.x;
        if (t < NUM_LAYERS) cnt[t] = 0;
        __syncthreads();
        for (int i = t; i < BATCH; i += 256) atomicAdd(&cnt[ids[i]], 1);
        __syncthreads();
        if (t == 0) {
            int a = 0;
            for (int l = 0; l < NUM_LAYERS; ++l) { off[l] = a; a += cnt[l]; }
        }
        __syncthreads();
        if (t < NUM_LAYERS) { cur[t] = 0; counts[t] = cnt[t]; offsets[t] = off[t]; }
        __syncthreads();
        for (int i = t; i < BATCH; i += 256) {
            int l = ids[i];
            int p = off[l] + atomicAdd(&cur[l], 1);
            perm[p] = i;
        }
    } else {
        const int base = (blockIdx.x - 1) * (BATCH * RANK / 64);
        for (int i = threadIdx.x; i < BATCH * RANK / 64; i += 256)
            proj[base + i] = 0.0f;
    }
}

// K1: proj[b,r] += sum_{h in chunk} z[b,h] * v[l,h,r]   via MFMA bf16
// A = Z (M=samples, K=h), B = V (K=h, N=r). Wave w owns r-tile w.
__global__ __launch_bounds__(256)
void k_proj(const float* __restrict__ z, const float* __restrict__ v,
            const int* __restrict__ counts, const int* __restrict__ offsets,
            const int* __restrict__ perm, float* __restrict__ proj)
{
    const int kc = blockIdx.x, l = blockIdx.y, sc = blockIdx.z;
    const int n = counts[l], o = offsets[l];
    if (sc * MB >= n) return;
    const int t = threadIdx.x;
    const int w = t >> 6, lane = t & 63;
    const int m16 = lane & 15, quad = lane >> 4;
    const int kbase = kc * KC;

    __shared__ ushort vt[RANK * VPAD];   // [r][h] bf16 transposed (~33 KB)
    __shared__ ushort zt[MB * ZPAD];     // [si][h] bf16 (~17 KB)
    __shared__ int    bidx[MB];

    // stage V slice transposed: coalesced float4 reads, once per block
    #pragma unroll
    for (int it = 0; it < 16; ++it) {
        const int idx = it * 256 + t;            // 4096 float4 = 256h x 16
        const int hh = idx >> 4, rq = idx & 15;
        const float4 uv = *(const float4*)
            &v[((size_t)l * HIDDEN + kbase + hh) * RANK + rq * 4];
        vt[(rq * 4 + 0) * VPAD + hh] = f2bf(uv.x);
        vt[(rq * 4 + 1) * VPAD + hh] = f2bf(uv.y);
        vt[(rq * 4 + 2) * VPAD + hh] = f2bf(uv.z);
        vt[(rq * 4 + 3) * VPAD + hh] = f2bf(uv.w);
    }

    for (int base = sc * MB; base < n; base += SCG * MB) {
        const int nb = (n - base < MB) ? (n - base) : MB;
        __syncthreads();                         // prior pass done with zt/bidx
        if (t < MB) bidx[t] = (t < nb) ? perm[o + base + t] : 0;
        __syncthreads();
        // stage 32 z-rows as bf16 (zero-padded beyond nb)
        #pragma unroll
        for (int it = 0; it < 8; ++it) {
            const int idx = it * 256 + t;        // 2048 float4 = 32si x 64
            const int si = idx >> 6, q = idx & 63;
            float4 zv = make_float4(0.f, 0.f, 0.f, 0.f);
            if (si < nb)
                zv = *(const float4*)&z[(size_t)bidx[si] * HIDDEN + kbase + q * 4];
            *(ushort4*)&zt[si * ZPAD + q * 4] = pack4(zv);
        }
        __syncthreads();

        f32x4 acc0 = {0.f, 0.f, 0.f, 0.f}, acc1 = {0.f, 0.f, 0.f, 0.f};
        #pragma unroll
        for (int kt = 0; kt < 8; ++kt) {
            const int koff = kt * 32 + quad * 8;
            const bf16x8 bf = *(const bf16x8*)&vt[(w * 16 + m16) * VPAD + koff];
            const bf16x8 a0 = *(const bf16x8*)&zt[m16 * ZPAD + koff];
            const bf16x8 a1 = *(const bf16x8*)&zt[(16 + m16) * ZPAD + koff];
            acc0 = __builtin_amdgcn_mfma_f32_16x16x32_bf16(a0, bf, acc0, 0, 0, 0);
            acc1 = __builtin_amdgcn_mfma_f32_16x16x32_bf16(a1, bf, acc1, 0, 0, 0);
        }
        // C/D: col(=r within tile)=lane&15, row(=si)=quad*4+reg
        const int r = w * 16 + m16;
        #pragma unroll
        for (int reg = 0; reg < 4; ++reg) {
            const int row = quad * 4 + reg;
            if (row < nb)
                atomicAdd(&proj[(size_t)bidx[row] * RANK + r], acc0[reg]);
            if (16 + row < nb)
                atomicAdd(&proj[(size_t)bidx[16 + row] * RANK + r], acc1[reg]);
        }
    }
}

// K2: out[b,h] = z[b,h] + sum_r proj[b,r] * u[l,h,r]   via MFMA bf16
// A = P (M=samples, K=r), B = U^T (K=r, N=h). U row-major [h][r] is exactly
// B's per-lane contiguous-k layout -> no transpose needed.
__global__ __launch_bounds__(256)
void k_delta(const float* __restrict__ z, const float* __restrict__ u,
             const int* __restrict__ counts, const int* __restrict__ offsets,
             const int* __restrict__ perm, const float* __restrict__ proj,
             float* __restrict__ out)
{
    const int hc = blockIdx.x, l = blockIdx.y, sc = blockIdx.z;
    const int n = counts[l], o = offsets[l];
    if (sc * MB >= n) return;
    const int t = threadIdx.x;
    const int w = t >> 6, lane = t & 63;
    const int m16 = lane & 15, quad = lane >> 4;
    const int hbase = hc * HCH;

    __shared__ ushort ut[HCH * UPAD];    // [h][r] bf16 (~37 KB)
    __shared__ ushort pt[MB * PPAD];     // [si][r] bf16 (~4.6 KB)
    __shared__ int    bidx[MB];

    // stage U slice: coalesced float4 reads, aligned ushort4 writes, once
    #pragma unroll
    for (int it = 0; it < 16; ++it) {
        const int idx = it * 256 + t;            // 4096 float4 = 256h x 16
        const int hh = idx >> 4, rq = idx & 15;
        const float4 uv = *(const float4*)
            &u[((size_t)l * HIDDEN + hbase + hh) * RANK + rq * 4];
        *(ushort4*)&ut[hh * UPAD + rq * 4] = pack4(uv);
    }

    for (int base = sc * MB; base < n; base += SCG * MB) {
        const int nb = (n - base < MB) ? (n - base) : MB;
        __syncthreads();
        if (t < MB) bidx[t] = (t < nb) ? perm[o + base + t] : 0;
        __syncthreads();
        #pragma unroll
        for (int it = 0; it < 2; ++it) {
            const int idx = it * 256 + t;        // 512 float4 = 32si x 16
            const int si = idx >> 4, rq = idx & 15;
            float4 pv = make_float4(0.f, 0.f, 0.f, 0.f);
            if (si < nb)
                pv = *(const float4*)&proj[(size_t)bidx[si] * RANK + rq * 4];
            *(ushort4*)&pt[si * PPAD + rq * 4] = pack4(pv);
        }
        __syncthreads();

        f32x4 acc[2][4];
        #pragma unroll
        for (int mt = 0; mt < 2; ++mt)
            #pragma unroll
            for (int nt = 0; nt < 4; ++nt)
                acc[mt][nt] = (f32x4){0.f, 0.f, 0.f, 0.f};

        #pragma unroll
        for (int kt = 0; kt < 2; ++kt) {
            const int koff = kt * 32 + quad * 8;
            const bf16x8 a0 = *(const bf16x8*)&pt[m16 * PPAD + koff];
            const bf16x8 a1 = *(const bf16x8*)&pt[(16 + m16) * PPAD + koff];
            #pragma unroll
            for (int nt = 0; nt < 4; ++nt) {
                const int h = (w * 4 + nt) * 16 + m16;
                const bf16x8 bf = *(const bf16x8*)&ut[h * UPAD + koff];
                acc[0][nt] = __builtin_amdgcn_mfma_f32_16x16x32_bf16(a0, bf, acc[0][nt], 0, 0, 0);
                acc[1][nt] = __builtin_amdgcn_mfma_f32_16x16x32_bf16(a1, bf, acc[1][nt], 0, 0, 0);
            }
        }
        // epilogue: out = z + delta
        #pragma unroll
        for (int mt = 0; mt < 2; ++mt) {
            #pragma unroll
            for (int reg = 0; reg < 4; ++reg) {
                const int si = mt * 16 + quad * 4 + reg;
                if (si < nb) {
                    const size_t rowb = (size_t)bidx[si] * HIDDEN + hbase;
                    #pragma unroll
                    for (int nt = 0; nt < 4; ++nt) {
                        const int h = (w * 4 + nt) * 16 + m16;
                        out[rowb + h] = z[rowb + h] + acc[mt][nt][reg];
                    }
                }
            }
        }
    }
}

extern "C" void kernel_launch(void* const* d_in, const int* in_sizes, int n_in,
                              void* d_out, int out_size, void* d_ws, size_t ws_size,
                              hipStream_t stream)
{
    const float* z   = (const float*)d_in[0];
    const int*   ids = (const int*)d_in[1];
    const float* u   = (const float*)d_in[2];
    const float* v   = (const float*)d_in[3];
    float* out = (float*)d_out;

    float* proj   = (float*)d_ws;                          // 512 KB
    int* counts   = (int*)(proj + (size_t)BATCH * RANK);
    int* offsets  = counts + NUM_LAYERS;
    int* perm     = offsets + NUM_LAYERS;

    hipLaunchKernelGGL(k_bucket_zero, dim3(65), dim3(256), 0, stream,
                       ids, proj, counts, offsets, perm);
    hipLaunchKernelGGL(k_proj, dim3(HIDDEN / KC, NUM_LAYERS, SCG), dim3(256), 0, stream,
                       z, v, counts, offsets, perm, proj);
    hipLaunchKernelGGL(k_delta, dim3(HIDDEN / HCH, NUM_LAYERS, SCG), dim3(256), 0, stream,
                       z, u, counts, offsets, perm, proj, out);
}